// Round 3
// baseline (544.814 us; speedup 1.0000x reference)
//
#include <hip/hip_runtime.h>

// Trilinear grid_pull, bound='zero', extrapolate=False.
// input: (B=2, C=2, 128,128,128) f32; grid: (B=2, 3, 128,128,128) f32 voxel coords
// out:   (B=2, C=2, 128,128,128) f32
//
// One thread handles 4 consecutive grid points (16B coalesced grid loads +
// output stores); both channels share the 8 tap indices (16 scalar gathers,
// served from L2/L3 since each channel volume is 8 MB). Grid loads and output
// stores are nontemporal: they are pure streams; keeping them out of L2
// preserves residency for the gathered input volume.

#define NDIM 128
#define NV   (128 * 128 * 128)   // 2097152 spatial voxels per (b,c) plane

typedef float f4 __attribute__((ext_vector_type(4)));  // native vector: legal
                                                       // for nontemporal builtins

__global__ __launch_bounds__(256) void grid_pull_kernel(
    const float* __restrict__ input,   // (B, C, NV)
    const float* __restrict__ grid,    // (B, 3, NV)
    float* __restrict__ out)           // (B, C, NV)
{
    const int t = blockIdx.x * blockDim.x + threadIdx.x;
    const int p4 = t << 2;                 // first of 4 points
    const int b  = p4 >> 21;               // p4 / NV  (NV = 2^21)
    const int s  = p4 & (NV - 1);          // spatial offset of first point

    const float* gbase = grid + (size_t)b * 3 * NV;
    const f4 gx = __builtin_nontemporal_load(
        reinterpret_cast<const f4*>(gbase + s));
    const f4 gy = __builtin_nontemporal_load(
        reinterpret_cast<const f4*>(gbase + NV + s));
    const f4 gz = __builtin_nontemporal_load(
        reinterpret_cast<const f4*>(gbase + 2 * NV + s));

    const float* in0 = input + (size_t)b * 2 * NV;   // channel 0
    const float* in1 = in0 + NV;                     // channel 1

    f4 o0, o1;

#pragma unroll
    for (int k = 0; k < 4; ++k) {
        const float x = gx[k];
        const float y = gy[k];
        const float z = gz[k];

        const float fx = floorf(x);
        const float fy = floorf(y);
        const float fz = floorf(z);
        const float wx = x - fx, wy = y - fy, wz = z - fz;
        const int ix = (int)fx, iy = (int)fy, iz = (int)fz;

        // extrapolate=False: zero anything sampled outside [0, N-1]^3.
        // NaN coords fail all comparisons -> inb=false -> 0 (matches ref).
        const bool inb = (x >= 0.0f) & (x <= (float)(NDIM - 1)) &
                         (y >= 0.0f) & (y <= (float)(NDIM - 1)) &
                         (z >= 0.0f) & (z <= (float)(NDIM - 1));

        float acc0 = 0.0f, acc1 = 0.0f;

        const bool interior = inb &
                              ((unsigned)ix < (unsigned)(NDIM - 1)) &
                              ((unsigned)iy < (unsigned)(NDIM - 1)) &
                              ((unsigned)iz < (unsigned)(NDIM - 1));
        if (interior) {
            // all 8 taps valid — straight-line gather + fma
            const int base = (ix << 14) + (iy << 7) + iz;
            const float* p0 = in0 + base;
            const float* p1 = in1 + base;

            const float wx0 = 1.0f - wx, wx1 = wx;
            const float wy0 = 1.0f - wy, wy1 = wy;
            const float wz0 = 1.0f - wz, wz1 = wz;
            const float w00 = wx0 * wy0, w01 = wx0 * wy1;
            const float w10 = wx1 * wy0, w11 = wx1 * wy1;
            const float w000 = w00 * wz0, w001 = w00 * wz1;
            const float w010 = w01 * wz0, w011 = w01 * wz1;
            const float w100 = w10 * wz0, w101 = w10 * wz1;
            const float w110 = w11 * wz0, w111 = w11 * wz1;

            // channel 0
            acc0 = p0[0] * w000;
            acc0 = fmaf(p0[1],             w001, acc0);
            acc0 = fmaf(p0[NDIM],          w010, acc0);
            acc0 = fmaf(p0[NDIM + 1],      w011, acc0);
            acc0 = fmaf(p0[NDIM * NDIM],       w100, acc0);
            acc0 = fmaf(p0[NDIM * NDIM + 1],   w101, acc0);
            acc0 = fmaf(p0[NDIM * NDIM + NDIM],     w110, acc0);
            acc0 = fmaf(p0[NDIM * NDIM + NDIM + 1], w111, acc0);
            // channel 1 (same indices)
            acc1 = p1[0] * w000;
            acc1 = fmaf(p1[1],             w001, acc1);
            acc1 = fmaf(p1[NDIM],          w010, acc1);
            acc1 = fmaf(p1[NDIM + 1],      w011, acc1);
            acc1 = fmaf(p1[NDIM * NDIM],       w100, acc1);
            acc1 = fmaf(p1[NDIM * NDIM + 1],   w101, acc1);
            acc1 = fmaf(p1[NDIM * NDIM + NDIM],     w110, acc1);
            acc1 = fmaf(p1[NDIM * NDIM + NDIM + 1], w111, acc1);
        } else if (inb) {
            // boundary: per-tap zero-bound handling (tap skipped if outside)
            for (int dx = 0; dx < 2; ++dx) {
                const int X = ix + dx;
                if ((unsigned)X >= (unsigned)NDIM) continue;
                const float wxd = dx ? wx : 1.0f - wx;
                for (int dy = 0; dy < 2; ++dy) {
                    const int Y = iy + dy;
                    if ((unsigned)Y >= (unsigned)NDIM) continue;
                    const float wyd = dy ? wy : 1.0f - wy;
                    for (int dz = 0; dz < 2; ++dz) {
                        const int Z = iz + dz;
                        if ((unsigned)Z >= (unsigned)NDIM) continue;
                        const float wzd = dz ? wz : 1.0f - wz;
                        const float wt = wxd * wyd * wzd;
                        const int idx = (X << 14) + (Y << 7) + Z;
                        acc0 = fmaf(in0[idx], wt, acc0);
                        acc1 = fmaf(in1[idx], wt, acc1);
                    }
                }
            }
        }
        o0[k] = acc0;
        o1[k] = acc1;
    }

    float* obase = out + (size_t)b * 2 * NV + s;
    __builtin_nontemporal_store(o0, reinterpret_cast<f4*>(obase));
    __builtin_nontemporal_store(o1, reinterpret_cast<f4*>(obase + NV));
}

extern "C" void kernel_launch(void* const* d_in, const int* in_sizes, int n_in,
                              void* d_out, int out_size, void* d_ws, size_t ws_size,
                              hipStream_t stream) {
    const float* input = (const float*)d_in[0];   // (2,2,128^3)
    const float* grid  = (const float*)d_in[1];   // (2,3,128^3)
    float* out         = (float*)d_out;           // (2,2,128^3)

    // 2 batches * NV points, 4 points/thread
    const int threads_total = (2 * NV) / 4;       // 1,048,576
    const int block = 256;
    const int ngrid = threads_total / block;      // 4096
    grid_pull_kernel<<<ngrid, block, 0, stream>>>(input, grid, out);
}

// Round 4
// 345.623 us; speedup vs baseline: 1.5763x; 1.5763x over previous
//
#include <hip/hip_runtime.h>

// Trilinear grid_pull, bound='zero', extrapolate=False.
// input: (B=2, C=2, 128^3) f32; grid: (B=2, 3, 128^3) f32 voxel coords.
//
// R3 data: 455 us, FETCH 1.69 GB (14x ideal), VALUBusy 1.6%, VGPR 28.
// Gathers miss the per-XCD 4 MiB L2 (16 MB working set) and each tap pair
// wastes its 64 B line (8 B used per channel). Fix:
//  1. repack input to channel-interleaved (B, V, C) in d_ws -> taps for both
//     channels at (z, z+1) are one 16 B span; lines/point ~8.8 -> ~4.6.
//  2. 3-phase gather kernel (addresses -> 32 float2 loads -> math) to keep
//     ~32 loads in flight per wave (was ~serialized at 28 VGPRs).

#define NDIM 128
#define NV   (128 * 128 * 128)   // 2^21 voxels per (b,c) volume

typedef float f4 __attribute__((ext_vector_type(4)));
typedef float f2 __attribute__((ext_vector_type(2)));

// ---------------- repack: (B,C,V) -> (B,V,C) ----------------
__global__ __launch_bounds__(256) void repack_kernel(
    const float* __restrict__ input, float* __restrict__ pk)
{
    const int t  = blockIdx.x * blockDim.x + threadIdx.x;
    const int v4 = t << 2;                // 4 voxels per thread
    const int b  = v4 >> 21;
    const int v  = v4 & (NV - 1);
    const float* base = input + (size_t)b * 2 * NV;
    const f4 a = *reinterpret_cast<const f4*>(base + v);        // c0
    const f4 c = *reinterpret_cast<const f4*>(base + NV + v);   // c1
    f4 w0, w1;
    w0.x = a.x; w0.y = c.x; w0.z = a.y; w0.w = c.y;
    w1.x = a.z; w1.y = c.z; w1.z = a.w; w1.w = c.w;
    float* o = pk + (size_t)b * 2 * NV + 2 * v;
    *reinterpret_cast<f4*>(o)     = w0;
    *reinterpret_cast<f4*>(o + 4) = w1;
}

// ---------------- gather from packed layout ----------------
__global__ __launch_bounds__(256) void grid_pull_packed_kernel(
    const float* __restrict__ pk,      // (B, V, 2) interleaved channels
    const float* __restrict__ grid,    // (B, 3, V)
    float* __restrict__ out)           // (B, C, V)
{
    const int t  = blockIdx.x * blockDim.x + threadIdx.x;
    const int p4 = t << 2;
    const int b  = p4 >> 21;
    const int s  = p4 & (NV - 1);

    const float* gbase = grid + (size_t)b * 3 * NV;
    const f4 gx = __builtin_nontemporal_load(reinterpret_cast<const f4*>(gbase + s));
    const f4 gy = __builtin_nontemporal_load(reinterpret_cast<const f4*>(gbase + NV + s));
    const f4 gz = __builtin_nontemporal_load(reinterpret_cast<const f4*>(gbase + 2 * NV + s));

    const float* p = pk + (size_t)b * 2 * NV;

    // phase 1: base addresses (clamped to 0 when not interior)
    int sbase[4];
#pragma unroll
    for (int k = 0; k < 4; ++k) {
        const int ix = (int)floorf(gx[k]);
        const int iy = (int)floorf(gy[k]);
        const int iz = (int)floorf(gz[k]);
        const bool interior = ((unsigned)ix < (unsigned)(NDIM - 1)) &
                              ((unsigned)iy < (unsigned)(NDIM - 1)) &
                              ((unsigned)iz < (unsigned)(NDIM - 1));
        const int base = (ix << 15) + (iy << 8) + (iz << 1);  // float index
        sbase[k] = interior ? base : 0;
    }

    // phase 2: all 32 float2 gathers issued back-to-back (MLP)
    // tap j: 0:(0,0,0) 1:(0,0,1) 2:(0,1,0) 3:(0,1,1) 4:(1,0,0) 5:(1,0,1) 6:(1,1,0) 7:(1,1,1)
    const int off[8] = {0, 2, 256, 258, 32768, 32770, 33024, 33026};
    f2 tv[4][8];
#pragma unroll
    for (int k = 0; k < 4; ++k) {
#pragma unroll
        for (int j = 0; j < 8; ++j) {
            tv[k][j] = *reinterpret_cast<const f2*>(p + sbase[k] + off[j]);
        }
    }

    // phase 3: weights + accumulate (+ rare boundary slow path)
    f4 o0, o1;
#pragma unroll
    for (int k = 0; k < 4; ++k) {
        const float x = gx[k], y = gy[k], z = gz[k];
        const float fx = floorf(x), fy = floorf(y), fz = floorf(z);
        const float wx = x - fx, wy = y - fy, wz = z - fz;
        const int ix = (int)fx, iy = (int)fy, iz = (int)fz;

        // extrapolate=False: zero anything outside [0, N-1]^3 (NaN -> 0 too)
        const bool inb = (x >= 0.0f) & (x <= (float)(NDIM - 1)) &
                         (y >= 0.0f) & (y <= (float)(NDIM - 1)) &
                         (z >= 0.0f) & (z <= (float)(NDIM - 1));
        const bool interior = inb &
                              ((unsigned)ix < (unsigned)(NDIM - 1)) &
                              ((unsigned)iy < (unsigned)(NDIM - 1)) &
                              ((unsigned)iz < (unsigned)(NDIM - 1));

        const float wx0 = 1.0f - wx, wy0 = 1.0f - wy, wz0 = 1.0f - wz;
        const float w00 = wx0 * wy0, w01 = wx0 * wy;
        const float w10 = wx  * wy0, w11 = wx  * wy;
        float wt[8];
        wt[0] = w00 * wz0; wt[1] = w00 * wz;
        wt[2] = w01 * wz0; wt[3] = w01 * wz;
        wt[4] = w10 * wz0; wt[5] = w10 * wz;
        wt[6] = w11 * wz0; wt[7] = w11 * wz;

        float acc0 = 0.0f, acc1 = 0.0f;
#pragma unroll
        for (int j = 0; j < 8; ++j) {
            acc0 = fmaf(tv[k][j].x, wt[j], acc0);
            acc1 = fmaf(tv[k][j].y, wt[j], acc1);
        }
        const float m = interior ? 1.0f : 0.0f;
        acc0 *= m; acc1 *= m;

        if (inb & !interior) {
            // boundary (statistically never for this input): per-tap zero bound
            acc0 = 0.0f; acc1 = 0.0f;
            for (int dx = 0; dx < 2; ++dx) {
                const int X = ix + dx;
                if ((unsigned)X >= (unsigned)NDIM) continue;
                const float wxd = dx ? wx : wx0;
                for (int dy = 0; dy < 2; ++dy) {
                    const int Y = iy + dy;
                    if ((unsigned)Y >= (unsigned)NDIM) continue;
                    const float wyd = dy ? wy : wy0;
                    for (int dz = 0; dz < 2; ++dz) {
                        const int Z = iz + dz;
                        if ((unsigned)Z >= (unsigned)NDIM) continue;
                        const float wzd = dz ? wz : wz0;
                        const float w = wxd * wyd * wzd;
                        const f2 v = *reinterpret_cast<const f2*>(
                            p + (X << 15) + (Y << 8) + (Z << 1));
                        acc0 = fmaf(v.x, w, acc0);
                        acc1 = fmaf(v.y, w, acc1);
                    }
                }
            }
        }
        o0[k] = acc0;
        o1[k] = acc1;
    }

    float* obase = out + (size_t)b * 2 * NV + s;
    __builtin_nontemporal_store(o0, reinterpret_cast<f4*>(obase));
    __builtin_nontemporal_store(o1, reinterpret_cast<f4*>(obase + NV));
}

// ---------------- fallback (original layout, no workspace) ----------------
__global__ __launch_bounds__(256) void grid_pull_direct_kernel(
    const float* __restrict__ input,
    const float* __restrict__ grid,
    float* __restrict__ out)
{
    const int t  = blockIdx.x * blockDim.x + threadIdx.x;
    const int p4 = t << 2;
    const int b  = p4 >> 21;
    const int s  = p4 & (NV - 1);

    const float* gbase = grid + (size_t)b * 3 * NV;
    const f4 gx = *reinterpret_cast<const f4*>(gbase + s);
    const f4 gy = *reinterpret_cast<const f4*>(gbase + NV + s);
    const f4 gz = *reinterpret_cast<const f4*>(gbase + 2 * NV + s);
    const float* in0 = input + (size_t)b * 2 * NV;
    const float* in1 = in0 + NV;

    f4 o0, o1;
#pragma unroll
    for (int k = 0; k < 4; ++k) {
        const float x = gx[k], y = gy[k], z = gz[k];
        const float fx = floorf(x), fy = floorf(y), fz = floorf(z);
        const float wx = x - fx, wy = y - fy, wz = z - fz;
        const int ix = (int)fx, iy = (int)fy, iz = (int)fz;
        const bool inb = (x >= 0.0f) & (x <= (float)(NDIM - 1)) &
                         (y >= 0.0f) & (y <= (float)(NDIM - 1)) &
                         (z >= 0.0f) & (z <= (float)(NDIM - 1));
        float acc0 = 0.0f, acc1 = 0.0f;
        if (inb) {
            for (int dx = 0; dx < 2; ++dx) {
                const int X = ix + dx;
                if ((unsigned)X >= (unsigned)NDIM) continue;
                const float wxd = dx ? wx : 1.0f - wx;
                for (int dy = 0; dy < 2; ++dy) {
                    const int Y = iy + dy;
                    if ((unsigned)Y >= (unsigned)NDIM) continue;
                    const float wyd = dy ? wy : 1.0f - wy;
                    for (int dz = 0; dz < 2; ++dz) {
                        const int Z = iz + dz;
                        if ((unsigned)Z >= (unsigned)NDIM) continue;
                        const float w = wxd * wyd * (dz ? wz : 1.0f - wz);
                        const int idx = (X << 14) + (Y << 7) + Z;
                        acc0 = fmaf(in0[idx], w, acc0);
                        acc1 = fmaf(in1[idx], w, acc1);
                    }
                }
            }
        }
        o0[k] = acc0;
        o1[k] = acc1;
    }
    float* obase = out + (size_t)b * 2 * NV + s;
    *reinterpret_cast<f4*>(obase)      = o0;
    *reinterpret_cast<f4*>(obase + NV) = o1;
}

extern "C" void kernel_launch(void* const* d_in, const int* in_sizes, int n_in,
                              void* d_out, int out_size, void* d_ws, size_t ws_size,
                              hipStream_t stream) {
    const float* input = (const float*)d_in[0];   // (2,2,128^3)
    const float* grid  = (const float*)d_in[1];   // (2,3,128^3)
    float* out         = (float*)d_out;           // (2,2,128^3)

    const int threads_total = (2 * NV) / 4;       // 1,048,576
    const int block = 256;
    const int ngrid = threads_total / block;      // 4096
    const size_t need = (size_t)2 * 2 * NV * sizeof(float);  // 33.6 MB packed

    if (ws_size >= need) {
        float* pk = (float*)d_ws;
        repack_kernel<<<ngrid, block, 0, stream>>>(input, pk);
        grid_pull_packed_kernel<<<ngrid, block, 0, stream>>>(pk, grid, out);
    } else {
        grid_pull_direct_kernel<<<ngrid, block, 0, stream>>>(input, grid, out);
    }
}

// Round 6
// 343.149 us; speedup vs baseline: 1.5877x; 1.0072x over previous
//
#include <hip/hip_runtime.h>

// Trilinear grid_pull, bound='zero', extrapolate=False.
// input: (B=2, C=2, 128^3) f32; grid: (B=2, 3, 128^3) f32 voxel coords.
//
// R4 evidence: replays with input fully L3-resident (FETCH 33 MB) run at the
// SAME 244 us as cold (862 MB) -> bound by L2-miss path (~3.7 TB/s random),
// time ~ proportional to miss count (R3/R4: 1.69GB/455us vs 862MB/246us).
// Only lever: raise L2 hit rate. This round: bin points by x-slab (16 bins,
// 2.1 MB contiguous input region each), gather slab-locally (bin->XCD via
// bid%8 heuristic), then unpermute results.
//
// ws layout: records f4[16*CAP] | pos int[NPTS] | res f2[16*CAP] | cursors
// Fallback: ws too small -> R4 packed path -> direct path.

#define NDIM 128
#define NV   (128 * 128 * 128)      // 2^21
#define NPTS (2 * NV)               // 4,194,304 points
#define NBINS 16                    // (batch 2) x (x-slab 8)  [slab depth 16]
#define CAP  270336                 // 262144 + 8192 (16 sigma slack)
#define NBLK 4096                   // NPTS / 1024

typedef float f4 __attribute__((ext_vector_type(4)));
typedef float f2 __attribute__((ext_vector_type(2)));
typedef int   i4 __attribute__((ext_vector_type(4)));

__device__ __forceinline__ int bin_of(float x, int b) {
    int ix = (int)floorf(x);               // NaN -> 0 (v_cvt_i32_f32), clamped below
    int slab = min(max(ix, 0), NDIM - 1) >> 4;
    return (b << 3) + slab;
}

// ---------------- P0: zero bin cursors ----------------
__global__ void p0_zero(int* __restrict__ cursor) {
    if (threadIdx.x < 64) cursor[threadIdx.x] = 0;
}

// ---------------- P3: scatter points into bins ----------------
__global__ __launch_bounds__(256) void p3_scatter(
    const float* __restrict__ grid,   // (B,3,NV)
    f4* __restrict__ rec,             // [NBINS*CAP] {x,y,z,bitcast(s)}
    int* __restrict__ pos,            // [NPTS] s -> d
    int* __restrict__ cursor)         // [NBINS]
{
    __shared__ int lcnt[NBINS];
    __shared__ int lbase[NBINS];
    const int t  = blockIdx.x * blockDim.x + threadIdx.x;
    const int p4 = t << 2;
    const int b  = p4 >> 21;
    const int s  = p4 & (NV - 1);

    if (threadIdx.x < NBINS) lcnt[threadIdx.x] = 0;
    __syncthreads();

    const float* gbase = grid + (size_t)b * 3 * NV;
    const f4 gx = __builtin_nontemporal_load(reinterpret_cast<const f4*>(gbase + s));
    const f4 gy = __builtin_nontemporal_load(reinterpret_cast<const f4*>(gbase + NV + s));
    const f4 gz = __builtin_nontemporal_load(reinterpret_cast<const f4*>(gbase + 2 * NV + s));

    int mybin[4], myrank[4];
#pragma unroll
    for (int k = 0; k < 4; ++k) {
        mybin[k]  = bin_of(gx[k], b);
        myrank[k] = atomicAdd(&lcnt[mybin[k]], 1);
    }
    __syncthreads();
    if (threadIdx.x < NBINS)
        lbase[threadIdx.x] = atomicAdd(&cursor[threadIdx.x], lcnt[threadIdx.x]);
    __syncthreads();

    i4 dvec;
#pragma unroll
    for (int k = 0; k < 4; ++k) {
        const int d = mybin[k] * CAP + lbase[mybin[k]] + myrank[k];
        f4 r;
        r.x = gx[k]; r.y = gy[k]; r.z = gz[k];
        r.w = __int_as_float(p4 + k);
        __builtin_nontemporal_store(r, &rec[d]);
        dvec[k] = d;
    }
    __builtin_nontemporal_store(dvec, reinterpret_cast<i4*>(pos + p4));
}

// ---------------- P4: slab-local gather ----------------
__global__ __launch_bounds__(256) void p4_gather(
    const float* __restrict__ input,  // (B,2,NV) original layout
    const f4* __restrict__ rec,
    f2* __restrict__ res,             // [NBINS*CAP]
    const int* __restrict__ cursor)   // final counts
{
    const int bid = blockIdx.x;
    // bins 0..7 first (one per XCD via bid%8 heuristic), then 8..15
    const int bin   = (bid < (NBLK / 2)) ? (bid & 7) : 8 + (bid & 7);
    const int chunk = (bid & (NBLK / 2 - 1)) >> 3;        // 0..255
    const int cnt   = cursor[bin];
    const int b     = bin >> 3;
    const int seg   = bin * CAP;
    const float* vin = input + (size_t)b * 2 * NV;

    for (int i = chunk * 1024 + (threadIdx.x << 2); i < cnt; i += 256 * 1024) {
#pragma unroll
        for (int k = 0; k < 4; ++k) {
            if (i + k >= cnt) break;
            const int d = seg + i + k;
            const f4 r = __builtin_nontemporal_load(&rec[d]);
            const float x = r.x, y = r.y, z = r.z;

            const float fx = floorf(x), fy = floorf(y), fz = floorf(z);
            const float wx = x - fx, wy = y - fy, wz = z - fz;
            const int ix = (int)fx, iy = (int)fy, iz = (int)fz;

            const bool inb = (x >= 0.0f) & (x <= (float)(NDIM - 1)) &
                             (y >= 0.0f) & (y <= (float)(NDIM - 1)) &
                             (z >= 0.0f) & (z <= (float)(NDIM - 1));
            const bool interior = inb &
                                  ((unsigned)ix < (unsigned)(NDIM - 1)) &
                                  ((unsigned)iy < (unsigned)(NDIM - 1)) &
                                  ((unsigned)iz < (unsigned)(NDIM - 1));
            float acc0 = 0.0f, acc1 = 0.0f;
            if (interior) {
                const int base = (ix << 14) + (iy << 7) + iz;
                const float wx0 = 1.0f - wx, wy0 = 1.0f - wy, wz0 = 1.0f - wz;
                const float w00 = wx0 * wy0, w01 = wx0 * wy;
                const float w10 = wx  * wy0, w11 = wx  * wy;
                const f2 a00 = *reinterpret_cast<const f2*>(vin + base);
                const f2 a01 = *reinterpret_cast<const f2*>(vin + base + 128);
                const f2 a10 = *reinterpret_cast<const f2*>(vin + base + 16384);
                const f2 a11 = *reinterpret_cast<const f2*>(vin + base + 16512);
                const f2 c00 = *reinterpret_cast<const f2*>(vin + NV + base);
                const f2 c01 = *reinterpret_cast<const f2*>(vin + NV + base + 128);
                const f2 c10 = *reinterpret_cast<const f2*>(vin + NV + base + 16384);
                const f2 c11 = *reinterpret_cast<const f2*>(vin + NV + base + 16512);
                // z-lerp then (x,y)-weighted sum
                const float z00 = fmaf(a00.y, wz, a00.x * wz0);
                const float z01 = fmaf(a01.y, wz, a01.x * wz0);
                const float z10 = fmaf(a10.y, wz, a10.x * wz0);
                const float z11 = fmaf(a11.y, wz, a11.x * wz0);
                acc0 = fmaf(z11, w11, fmaf(z10, w10, fmaf(z01, w01, z00 * w00)));
                const float u00 = fmaf(c00.y, wz, c00.x * wz0);
                const float u01 = fmaf(c01.y, wz, c01.x * wz0);
                const float u10 = fmaf(c10.y, wz, c10.x * wz0);
                const float u11 = fmaf(c11.y, wz, c11.x * wz0);
                acc1 = fmaf(u11, w11, fmaf(u10, w10, fmaf(u01, w01, u00 * w00)));
            } else if (inb) {
                // boundary: per-tap zero-bound
                for (int dx = 0; dx < 2; ++dx) {
                    const int X = ix + dx;
                    if ((unsigned)X >= (unsigned)NDIM) continue;
                    const float wxd = dx ? wx : 1.0f - wx;
                    for (int dy = 0; dy < 2; ++dy) {
                        const int Y = iy + dy;
                        if ((unsigned)Y >= (unsigned)NDIM) continue;
                        const float wyd = dy ? wy : 1.0f - wy;
                        for (int dz = 0; dz < 2; ++dz) {
                            const int Z = iz + dz;
                            if ((unsigned)Z >= (unsigned)NDIM) continue;
                            const float w = wxd * wyd * (dz ? wz : 1.0f - wz);
                            const int idx = (X << 14) + (Y << 7) + Z;
                            acc0 = fmaf(vin[idx], w, acc0);
                            acc1 = fmaf(vin[NV + idx], w, acc1);
                        }
                    }
                }
            }
            f2 o; o.x = acc0; o.y = acc1;
            res[d] = o;   // normal store: want it cached (L3) for P5
        }
    }
}

// ---------------- P5: unpermute res -> out ----------------
__global__ __launch_bounds__(256) void p5_unpermute(
    const f2* __restrict__ res,
    const int* __restrict__ pos,
    float* __restrict__ out)          // (B,2,NV)
{
    const int t  = blockIdx.x * blockDim.x + threadIdx.x;
    const int p4 = t << 2;
    const int b  = p4 >> 21;
    const int s  = p4 & (NV - 1);

    const i4 dd = __builtin_nontemporal_load(reinterpret_cast<const i4*>(pos + p4));
    const f2 r0 = res[dd.x];
    const f2 r1 = res[dd.y];
    const f2 r2 = res[dd.z];
    const f2 r3 = res[dd.w];
    f4 o0, o1;
    o0.x = r0.x; o0.y = r1.x; o0.z = r2.x; o0.w = r3.x;
    o1.x = r0.y; o1.y = r1.y; o1.z = r2.y; o1.w = r3.y;
    float* obase = out + (size_t)b * 2 * NV + s;
    __builtin_nontemporal_store(o0, reinterpret_cast<f4*>(obase));
    __builtin_nontemporal_store(o1, reinterpret_cast<f4*>(obase + NV));
}

// ================= fallback paths (R4) =================
__global__ __launch_bounds__(256) void repack_kernel(
    const float* __restrict__ input, float* __restrict__ pk)
{
    const int t  = blockIdx.x * blockDim.x + threadIdx.x;
    const int v4 = t << 2;
    const int b  = v4 >> 21;
    const int v  = v4 & (NV - 1);
    const float* base = input + (size_t)b * 2 * NV;
    const f4 a = *reinterpret_cast<const f4*>(base + v);
    const f4 c = *reinterpret_cast<const f4*>(base + NV + v);
    f4 w0, w1;
    w0.x = a.x; w0.y = c.x; w0.z = a.y; w0.w = c.y;
    w1.x = a.z; w1.y = c.z; w1.z = a.w; w1.w = c.w;
    float* o = pk + (size_t)b * 2 * NV + 2 * v;
    *reinterpret_cast<f4*>(o)     = w0;
    *reinterpret_cast<f4*>(o + 4) = w1;
}

__global__ __launch_bounds__(256) void grid_pull_packed_kernel(
    const float* __restrict__ pk,
    const float* __restrict__ grid,
    float* __restrict__ out)
{
    const int t  = blockIdx.x * blockDim.x + threadIdx.x;
    const int p4 = t << 2;
    const int b  = p4 >> 21;
    const int s  = p4 & (NV - 1);
    const float* gbase = grid + (size_t)b * 3 * NV;
    const f4 gx = *reinterpret_cast<const f4*>(gbase + s);
    const f4 gy = *reinterpret_cast<const f4*>(gbase + NV + s);
    const f4 gz = *reinterpret_cast<const f4*>(gbase + 2 * NV + s);
    const float* p = pk + (size_t)b * 2 * NV;

    f4 o0, o1;
#pragma unroll
    for (int k = 0; k < 4; ++k) {
        const float x = gx[k], y = gy[k], z = gz[k];
        const float fx = floorf(x), fy = floorf(y), fz = floorf(z);
        const float wx = x - fx, wy = y - fy, wz = z - fz;
        const int ix = (int)fx, iy = (int)fy, iz = (int)fz;
        const bool inb = (x >= 0.0f) & (x <= (float)(NDIM - 1)) &
                         (y >= 0.0f) & (y <= (float)(NDIM - 1)) &
                         (z >= 0.0f) & (z <= (float)(NDIM - 1));
        float acc0 = 0.0f, acc1 = 0.0f;
        if (inb) {
            for (int dx = 0; dx < 2; ++dx) {
                const int X = ix + dx;
                if ((unsigned)X >= (unsigned)NDIM) continue;
                const float wxd = dx ? wx : 1.0f - wx;
                for (int dy = 0; dy < 2; ++dy) {
                    const int Y = iy + dy;
                    if ((unsigned)Y >= (unsigned)NDIM) continue;
                    const float wyd = dy ? wy : 1.0f - wy;
                    for (int dz = 0; dz < 2; ++dz) {
                        const int Z = iz + dz;
                        if ((unsigned)Z >= (unsigned)NDIM) continue;
                        const float w = wxd * wyd * (dz ? wz : 1.0f - wz);
                        const f2 v = *reinterpret_cast<const f2*>(
                            p + (X << 15) + (Y << 8) + (Z << 1));
                        acc0 = fmaf(v.x, w, acc0);
                        acc1 = fmaf(v.y, w, acc1);
                    }
                }
            }
        }
        o0[k] = acc0; o1[k] = acc1;
    }
    float* obase = out + (size_t)b * 2 * NV + s;
    *reinterpret_cast<f4*>(obase)      = o0;
    *reinterpret_cast<f4*>(obase + NV) = o1;
}

__global__ __launch_bounds__(256) void grid_pull_direct_kernel(
    const float* __restrict__ input,
    const float* __restrict__ grid,
    float* __restrict__ out)
{
    const int t  = blockIdx.x * blockDim.x + threadIdx.x;
    const int p4 = t << 2;
    const int b  = p4 >> 21;
    const int s  = p4 & (NV - 1);
    const float* gbase = grid + (size_t)b * 3 * NV;
    const f4 gx = *reinterpret_cast<const f4*>(gbase + s);
    const f4 gy = *reinterpret_cast<const f4*>(gbase + NV + s);
    const f4 gz = *reinterpret_cast<const f4*>(gbase + 2 * NV + s);
    const float* in0 = input + (size_t)b * 2 * NV;
    const float* in1 = in0 + NV;
    f4 o0, o1;
#pragma unroll
    for (int k = 0; k < 4; ++k) {
        const float x = gx[k], y = gy[k], z = gz[k];
        const float fx = floorf(x), fy = floorf(y), fz = floorf(z);
        const float wx = x - fx, wy = y - fy, wz = z - fz;
        const int ix = (int)fx, iy = (int)fy, iz = (int)fz;
        const bool inb = (x >= 0.0f) & (x <= (float)(NDIM - 1)) &
                         (y >= 0.0f) & (y <= (float)(NDIM - 1)) &
                         (z >= 0.0f) & (z <= (float)(NDIM - 1));
        float acc0 = 0.0f, acc1 = 0.0f;
        if (inb) {
            for (int dx = 0; dx < 2; ++dx) {
                const int X = ix + dx;
                if ((unsigned)X >= (unsigned)NDIM) continue;
                const float wxd = dx ? wx : 1.0f - wx;
                for (int dy = 0; dy < 2; ++dy) {
                    const int Y = iy + dy;
                    if ((unsigned)Y >= (unsigned)NDIM) continue;
                    const float wyd = dy ? wy : 1.0f - wy;
                    for (int dz = 0; dz < 2; ++dz) {
                        const int Z = iz + dz;
                        if ((unsigned)Z >= (unsigned)NDIM) continue;
                        const float w = wxd * wyd * (dz ? wz : 1.0f - wz);
                        const int idx = (X << 14) + (Y << 7) + Z;
                        acc0 = fmaf(in0[idx], w, acc0);
                        acc1 = fmaf(in1[idx], w, acc1);
                    }
                }
            }
        }
        o0[k] = acc0; o1[k] = acc1;
    }
    float* obase = out + (size_t)b * 2 * NV + s;
    *reinterpret_cast<f4*>(obase)      = o0;
    *reinterpret_cast<f4*>(obase + NV) = o1;
}

extern "C" void kernel_launch(void* const* d_in, const int* in_sizes, int n_in,
                              void* d_out, int out_size, void* d_ws, size_t ws_size,
                              hipStream_t stream) {
    const float* input = (const float*)d_in[0];   // (2,2,128^3)
    const float* grid  = (const float*)d_in[1];   // (2,3,128^3)
    float* out         = (float*)d_out;           // (2,2,128^3)

    const size_t rec_bytes  = (size_t)NBINS * CAP * sizeof(f4);   // 69.2 MB
    const size_t pos_bytes  = (size_t)NPTS * sizeof(int);         // 16.8 MB
    const size_t res_bytes  = (size_t)NBINS * CAP * sizeof(f2);   // 34.6 MB
    const size_t cur_bytes  = 256;
    const size_t need_bin   = rec_bytes + pos_bytes + res_bytes + cur_bytes; // ~120.6 MB
    const size_t need_pack  = (size_t)2 * 2 * NV * sizeof(float); // 33.6 MB

    const int block = 256;

    if (ws_size >= need_bin) {
        char* w = (char*)d_ws;
        f4*  rec    = (f4*)w;
        int* pos    = (int*)(w + rec_bytes);
        f2*  res    = (f2*)(w + rec_bytes + pos_bytes);
        int* cursor = (int*)(w + rec_bytes + pos_bytes + res_bytes);

        p0_zero<<<1, 64, 0, stream>>>(cursor);
        p3_scatter<<<NBLK, block, 0, stream>>>(grid, rec, pos, cursor);
        p4_gather<<<NBLK, block, 0, stream>>>(input, rec, res, cursor);
        p5_unpermute<<<NBLK, block, 0, stream>>>(res, pos, out);
    } else if (ws_size >= need_pack) {
        float* pk = (float*)d_ws;
        repack_kernel<<<NBLK, block, 0, stream>>>(input, pk);
        grid_pull_packed_kernel<<<NBLK, block, 0, stream>>>(pk, grid, out);
    } else {
        grid_pull_direct_kernel<<<NBLK, block, 0, stream>>>(input, grid, out);
    }
}

// Round 7
// 298.374 us; speedup vs baseline: 1.8259x; 1.1501x over previous
//
#include <hip/hip_runtime.h>

// Trilinear grid_pull, bound='zero', extrapolate=False.
// input: (B=2, C=2, 128^3) f32; grid: (B=2, 3, 128^3) f32 voxel coords.
//
// R6 evidence: binning fixed traffic (FETCH 862->164 MB) but p4_gather=190us
// at 1.58 TB/s, VALU 3.5% -> bound by lane-transaction rate (33.5M scattered
// f2 loads) + serialized chains (VGPR=20, break-in-unroll). This round:
//  - repack input to (V, C) interleaved per batch: one f4 load = both
//    channels x (z,z+1) -> 4 taps/point instead of 8.
//  - 3-phase p4 (rec loads | tap loads | math), branchless tail -> MLP.
//  - per-batch pipeline (buffers reused b=0 then b=1): ws 77 MB < 120.6 MB
//    known-available.

#define NDIM  128
#define NV    (128 * 128 * 128)     // 2^21 voxels / points per batch
#define NPTS  (2 * NV)
#define NSLAB 8                     // x-slabs of depth 16 per batch
#define CAP   270336                // 262144 mean + ~17 sigma
#define NBLKB 2048                  // NV / 1024

typedef float f4 __attribute__((ext_vector_type(4)));
typedef float f2 __attribute__((ext_vector_type(2)));
typedef int   i4 __attribute__((ext_vector_type(4)));

// ---------------- P0: zero slab cursors ----------------
__global__ void p0_zero(int* __restrict__ cursor) {
    if (threadIdx.x < NSLAB) cursor[threadIdx.x] = 0;
}

// ---------------- P2: repack one batch (C,V) -> (V,C) ----------------
__global__ __launch_bounds__(256) void p2_repack(
    const float* __restrict__ inb,   // input + b*2*NV
    float* __restrict__ pk)          // [2*NV] interleaved
{
    const int t  = blockIdx.x * blockDim.x + threadIdx.x;
    const int v  = t << 2;
    const f4 a = *reinterpret_cast<const f4*>(inb + v);        // c0
    const f4 c = *reinterpret_cast<const f4*>(inb + NV + v);   // c1
    f4 w0, w1;
    w0.x = a.x; w0.y = c.x; w0.z = a.y; w0.w = c.y;
    w1.x = a.z; w1.y = c.z; w1.z = a.w; w1.w = c.w;
    float* o = pk + 2 * v;
    *reinterpret_cast<f4*>(o)     = w0;
    *reinterpret_cast<f4*>(o + 4) = w1;
}

// ---------------- P3: scatter one batch's points into slabs ----------------
__global__ __launch_bounds__(256) void p3_scatter(
    const float* __restrict__ gb,    // grid + b*3*NV
    f4* __restrict__ rec,            // [NSLAB*CAP] {x,y,z,bitcast(s)}
    int* __restrict__ pos,           // [NV] s -> d
    int* __restrict__ cursor)        // [NSLAB]
{
    __shared__ int lcnt[NSLAB];
    __shared__ int lbase[NSLAB];
    const int t = blockIdx.x * blockDim.x + threadIdx.x;
    const int s = t << 2;

    if (threadIdx.x < NSLAB) lcnt[threadIdx.x] = 0;
    __syncthreads();

    const f4 gx = __builtin_nontemporal_load(reinterpret_cast<const f4*>(gb + s));
    const f4 gy = __builtin_nontemporal_load(reinterpret_cast<const f4*>(gb + NV + s));
    const f4 gz = __builtin_nontemporal_load(reinterpret_cast<const f4*>(gb + 2 * NV + s));

    int mybin[4], myrank[4];
#pragma unroll
    for (int k = 0; k < 4; ++k) {
        const int ix = (int)floorf(gx[k]);             // NaN -> 0
        mybin[k]  = min(max(ix, 0), NDIM - 1) >> 4;
        myrank[k] = atomicAdd(&lcnt[mybin[k]], 1);
    }
    __syncthreads();
    if (threadIdx.x < NSLAB)
        lbase[threadIdx.x] = atomicAdd(&cursor[threadIdx.x], lcnt[threadIdx.x]);
    __syncthreads();

    i4 dvec;
#pragma unroll
    for (int k = 0; k < 4; ++k) {
        const int d = mybin[k] * CAP + lbase[mybin[k]] + myrank[k];
        f4 r;
        r.x = gx[k]; r.y = gy[k]; r.z = gz[k];
        r.w = __int_as_float(s + k);
        __builtin_nontemporal_store(r, &rec[d]);
        dvec[k] = d;
    }
    __builtin_nontemporal_store(dvec, reinterpret_cast<i4*>(pos + s));
}

// ---------------- P4: slab-local gather from packed volume ----------------
__global__ __launch_bounds__(256) void p4_gather(
    const float* __restrict__ pk,    // [2*NV] (V,C) interleaved
    const f4* __restrict__ rec,
    f2* __restrict__ res,            // [NSLAB*CAP]
    const int* __restrict__ cursor)
{
    const int bin   = blockIdx.x & 7;          // bin -> XCD via bid%8 heuristic
    const int chunk = blockIdx.x >> 3;         // 0..255
    const int cnt   = cursor[bin];
    const int seg   = bin * CAP;

    for (int i = chunk * 1024 + (threadIdx.x << 2); i < cnt; i += 256 * 1024) {
        // phase A: 4 rec loads, address-clamped (stores predicated later)
        bool live[4];
        f4 r[4];
#pragma unroll
        for (int k = 0; k < 4; ++k) {
            live[k] = (i + k) < cnt;
            r[k] = rec[live[k] ? (seg + i + k) : seg];
        }
        // phase B: 16 tap loads (4 f4 per point: both channels x (z,z+1))
        f4 t00[4], t01[4], t10[4], t11[4];
        bool inb[4], interior[4];
        float wx[4], wy[4], wz[4];
        int ixa[4], iya[4], iza[4];
#pragma unroll
        for (int k = 0; k < 4; ++k) {
            const float x = r[k].x, y = r[k].y, z = r[k].z;
            const float fx = floorf(x), fy = floorf(y), fz = floorf(z);
            wx[k] = x - fx; wy[k] = y - fy; wz[k] = z - fz;
            const int ix = (int)fx, iy = (int)fy, iz = (int)fz;
            ixa[k] = ix; iya[k] = iy; iza[k] = iz;
            inb[k] = (x >= 0.0f) & (x <= (float)(NDIM - 1)) &
                     (y >= 0.0f) & (y <= (float)(NDIM - 1)) &
                     (z >= 0.0f) & (z <= (float)(NDIM - 1));
            interior[k] = inb[k] &
                          ((unsigned)ix < (unsigned)(NDIM - 1)) &
                          ((unsigned)iy < (unsigned)(NDIM - 1)) &
                          ((unsigned)iz < (unsigned)(NDIM - 1));
            const int base = interior[k] ? ((ix << 14) + (iy << 7) + iz) : 0;
            const f4* q = reinterpret_cast<const f4*>(pk + 2 * base);
            t00[k] = q[0];          // (x  ,y  ): {c0[z],c1[z],c0[z+1],c1[z+1]}
            t01[k] = q[64];         // (x  ,y+1): +2*128 floats
            t10[k] = q[8192];       // (x+1,y  ): +2*16384 floats
            t11[k] = q[8256];       // (x+1,y+1)
        }
        // phase C: math + predicated store
#pragma unroll
        for (int k = 0; k < 4; ++k) {
            float acc0 = 0.0f, acc1 = 0.0f;
            const float wz0 = 1.0f - wz[k];
            if (interior[k]) {
                const float wx0 = 1.0f - wx[k], wy0 = 1.0f - wy[k];
                const float w00 = wx0 * wy0,  w01 = wx0 * wy[k];
                const float w10 = wx[k] * wy0, w11 = wx[k] * wy[k];
                // z-lerp per (x,y) corner, channels in lanes {x,y} vs {z,w}
                const float z00a = fmaf(t00[k].z, wz[k], t00[k].x * wz0);
                const float z01a = fmaf(t01[k].z, wz[k], t01[k].x * wz0);
                const float z10a = fmaf(t10[k].z, wz[k], t10[k].x * wz0);
                const float z11a = fmaf(t11[k].z, wz[k], t11[k].x * wz0);
                acc0 = fmaf(z11a, w11, fmaf(z10a, w10, fmaf(z01a, w01, z00a * w00)));
                const float z00b = fmaf(t00[k].w, wz[k], t00[k].y * wz0);
                const float z01b = fmaf(t01[k].w, wz[k], t01[k].y * wz0);
                const float z10b = fmaf(t10[k].w, wz[k], t10[k].y * wz0);
                const float z11b = fmaf(t11[k].w, wz[k], t11[k].y * wz0);
                acc1 = fmaf(z11b, w11, fmaf(z10b, w10, fmaf(z01b, w01, z00b * w00)));
            } else if (inb[k]) {
                // boundary: per-tap zero-bound from packed volume
                for (int dx = 0; dx < 2; ++dx) {
                    const int X = ixa[k] + dx;
                    if ((unsigned)X >= (unsigned)NDIM) continue;
                    const float wxd = dx ? wx[k] : 1.0f - wx[k];
                    for (int dy = 0; dy < 2; ++dy) {
                        const int Y = iya[k] + dy;
                        if ((unsigned)Y >= (unsigned)NDIM) continue;
                        const float wyd = dy ? wy[k] : 1.0f - wy[k];
                        for (int dz = 0; dz < 2; ++dz) {
                            const int Z = iza[k] + dz;
                            if ((unsigned)Z >= (unsigned)NDIM) continue;
                            const float w = wxd * wyd * (dz ? wz[k] : wz0);
                            const f2 v = *reinterpret_cast<const f2*>(
                                pk + 2 * ((X << 14) + (Y << 7) + Z));
                            acc0 = fmaf(v.x, w, acc0);
                            acc1 = fmaf(v.y, w, acc1);
                        }
                    }
                }
            }
            if (live[k]) {
                f2 o; o.x = acc0; o.y = acc1;
                res[seg + i + k] = o;
            }
        }
    }
}

// ---------------- P5: unpermute one batch ----------------
__global__ __launch_bounds__(256) void p5_unpermute(
    const f2* __restrict__ res,
    const int* __restrict__ pos,
    float* __restrict__ outb)        // out + b*2*NV
{
    const int t = blockIdx.x * blockDim.x + threadIdx.x;
    const int s = t << 2;
    const i4 dd = __builtin_nontemporal_load(reinterpret_cast<const i4*>(pos + s));
    const f2 r0 = res[dd.x];
    const f2 r1 = res[dd.y];
    const f2 r2 = res[dd.z];
    const f2 r3 = res[dd.w];
    f4 o0, o1;
    o0.x = r0.x; o0.y = r1.x; o0.z = r2.x; o0.w = r3.x;
    o1.x = r0.y; o1.y = r1.y; o1.z = r2.y; o1.w = r3.y;
    __builtin_nontemporal_store(o0, reinterpret_cast<f4*>(outb + s));
    __builtin_nontemporal_store(o1, reinterpret_cast<f4*>(outb + NV + s));
}

// ================= fallback paths =================
__global__ __launch_bounds__(256) void grid_pull_packed_kernel(
    const float* __restrict__ pk,    // full (B,V,C): repacked both batches
    const float* __restrict__ grid,
    float* __restrict__ out)
{
    const int t  = blockIdx.x * blockDim.x + threadIdx.x;
    const int p4i = t << 2;
    const int b  = p4i >> 21;
    const int s  = p4i & (NV - 1);
    const float* gbase = grid + (size_t)b * 3 * NV;
    const f4 gx = *reinterpret_cast<const f4*>(gbase + s);
    const f4 gy = *reinterpret_cast<const f4*>(gbase + NV + s);
    const f4 gz = *reinterpret_cast<const f4*>(gbase + 2 * NV + s);
    const float* p = pk + (size_t)b * 2 * NV;
    f4 o0, o1;
#pragma unroll
    for (int k = 0; k < 4; ++k) {
        const float x = gx[k], y = gy[k], z = gz[k];
        const float fx = floorf(x), fy = floorf(y), fz = floorf(z);
        const float wx = x - fx, wy = y - fy, wz = z - fz;
        const int ix = (int)fx, iy = (int)fy, iz = (int)fz;
        const bool inb = (x >= 0.0f) & (x <= (float)(NDIM - 1)) &
                         (y >= 0.0f) & (y <= (float)(NDIM - 1)) &
                         (z >= 0.0f) & (z <= (float)(NDIM - 1));
        float acc0 = 0.0f, acc1 = 0.0f;
        if (inb) {
            for (int dx = 0; dx < 2; ++dx) {
                const int X = ix + dx;
                if ((unsigned)X >= (unsigned)NDIM) continue;
                const float wxd = dx ? wx : 1.0f - wx;
                for (int dy = 0; dy < 2; ++dy) {
                    const int Y = iy + dy;
                    if ((unsigned)Y >= (unsigned)NDIM) continue;
                    const float wyd = dy ? wy : 1.0f - wy;
                    for (int dz = 0; dz < 2; ++dz) {
                        const int Z = iz + dz;
                        if ((unsigned)Z >= (unsigned)NDIM) continue;
                        const float w = wxd * wyd * (dz ? wz : 1.0f - wz);
                        const f2 v = *reinterpret_cast<const f2*>(
                            p + (X << 15) + (Y << 8) + (Z << 1));
                        acc0 = fmaf(v.x, w, acc0);
                        acc1 = fmaf(v.y, w, acc1);
                    }
                }
            }
        }
        o0[k] = acc0; o1[k] = acc1;
    }
    float* obase = out + (size_t)b * 2 * NV + s;
    *reinterpret_cast<f4*>(obase)      = o0;
    *reinterpret_cast<f4*>(obase + NV) = o1;
}

__global__ __launch_bounds__(256) void grid_pull_direct_kernel(
    const float* __restrict__ input,
    const float* __restrict__ grid,
    float* __restrict__ out)
{
    const int t  = blockIdx.x * blockDim.x + threadIdx.x;
    const int p4i = t << 2;
    const int b  = p4i >> 21;
    const int s  = p4i & (NV - 1);
    const float* gbase = grid + (size_t)b * 3 * NV;
    const f4 gx = *reinterpret_cast<const f4*>(gbase + s);
    const f4 gy = *reinterpret_cast<const f4*>(gbase + NV + s);
    const f4 gz = *reinterpret_cast<const f4*>(gbase + 2 * NV + s);
    const float* in0 = input + (size_t)b * 2 * NV;
    const float* in1 = in0 + NV;
    f4 o0, o1;
#pragma unroll
    for (int k = 0; k < 4; ++k) {
        const float x = gx[k], y = gy[k], z = gz[k];
        const float fx = floorf(x), fy = floorf(y), fz = floorf(z);
        const float wx = x - fx, wy = y - fy, wz = z - fz;
        const int ix = (int)fx, iy = (int)fy, iz = (int)fz;
        const bool inb = (x >= 0.0f) & (x <= (float)(NDIM - 1)) &
                         (y >= 0.0f) & (y <= (float)(NDIM - 1)) &
                         (z >= 0.0f) & (z <= (float)(NDIM - 1));
        float acc0 = 0.0f, acc1 = 0.0f;
        if (inb) {
            for (int dx = 0; dx < 2; ++dx) {
                const int X = ix + dx;
                if ((unsigned)X >= (unsigned)NDIM) continue;
                const float wxd = dx ? wx : 1.0f - wx;
                for (int dy = 0; dy < 2; ++dy) {
                    const int Y = iy + dy;
                    if ((unsigned)Y >= (unsigned)NDIM) continue;
                    const float wyd = dy ? wy : 1.0f - wy;
                    for (int dz = 0; dz < 2; ++dz) {
                        const int Z = iz + dz;
                        if ((unsigned)Z >= (unsigned)NDIM) continue;
                        const float w = wxd * wyd * (dz ? wz : 1.0f - wz);
                        const int idx = (X << 14) + (Y << 7) + Z;
                        acc0 = fmaf(in0[idx], w, acc0);
                        acc1 = fmaf(in1[idx], w, acc1);
                    }
                }
            }
        }
        o0[k] = acc0; o1[k] = acc1;
    }
    float* obase = out + (size_t)b * 2 * NV + s;
    *reinterpret_cast<f4*>(obase)      = o0;
    *reinterpret_cast<f4*>(obase + NV) = o1;
}

extern "C" void kernel_launch(void* const* d_in, const int* in_sizes, int n_in,
                              void* d_out, int out_size, void* d_ws, size_t ws_size,
                              hipStream_t stream) {
    const float* input = (const float*)d_in[0];   // (2,2,128^3)
    const float* grid  = (const float*)d_in[1];   // (2,3,128^3)
    float* out         = (float*)d_out;           // (2,2,128^3)

    const size_t rec_bytes = (size_t)NSLAB * CAP * sizeof(f4);    // 34.6 MB
    const size_t res_bytes = (size_t)NSLAB * CAP * sizeof(f2);    // 17.3 MB
    const size_t pk_bytes  = (size_t)2 * NV * sizeof(float);      // 16.8 MB
    const size_t pos_bytes = (size_t)NV * sizeof(int);            //  8.4 MB
    const size_t need_bin  = rec_bytes + res_bytes + pk_bytes + pos_bytes + 256;
    const size_t need_pack = (size_t)2 * 2 * NV * sizeof(float);  // 33.6 MB

    const int block = 256;

    if (ws_size >= need_bin) {                    // ~77.2 MB
        char* w = (char*)d_ws;
        f4*   rec    = (f4*)w;
        f2*   res    = (f2*)(w + rec_bytes);
        float* pk    = (float*)(w + rec_bytes + res_bytes);
        int*  pos    = (int*)(w + rec_bytes + res_bytes + pk_bytes);
        int*  cursor = (int*)(w + rec_bytes + res_bytes + pk_bytes + pos_bytes);

        for (int b = 0; b < 2; ++b) {
            const float* inb = input + (size_t)b * 2 * NV;
            const float* gb  = grid  + (size_t)b * 3 * NV;
            float* outb      = out   + (size_t)b * 2 * NV;
            p0_zero<<<1, 64, 0, stream>>>(cursor);
            p2_repack<<<NBLKB, block, 0, stream>>>(inb, pk);
            p3_scatter<<<NBLKB, block, 0, stream>>>(gb, rec, pos, cursor);
            p4_gather<<<NBLKB, block, 0, stream>>>(pk, rec, res, cursor);
            p5_unpermute<<<NBLKB, block, 0, stream>>>(res, pos, outb);
        }
    } else if (ws_size >= need_pack) {
        // repack both batches then direct packed gather (R4 path)
        float* pk = (float*)d_ws;
        for (int b = 0; b < 2; ++b)
            p2_repack<<<NBLKB, block, 0, stream>>>(input + (size_t)b * 2 * NV,
                                                   pk + (size_t)b * 2 * NV);
        grid_pull_packed_kernel<<<2 * NBLKB, block, 0, stream>>>(pk, grid, out);
    } else {
        grid_pull_direct_kernel<<<2 * NBLKB, block, 0, stream>>>(input, grid, out);
    }
}